// Round 9
// baseline (117.644 us; speedup 1.0000x reference)
//
#include <hip/hip_runtime.h>
#include <math.h>

#define B_   32
#define C_   64
#define H_   224
#define W_   224
#define HW_  (H_*W_)          // 50176
#define HW4_ (HW_/4)          // 12544
#define G_   36
#define CHUNKS_ 28
#define ROWS_ 8               // rows per chunk; 28*8 = 224
#define SEGW_ 7               // pixels per thread segment; 32 segs * 7 = 224

typedef float f4v __attribute__((ext_vector_type(4)));

// ---------------- kernel 1: channel mean (R6 form + per-block channel-start swizzle) ----------------
// Same coalescing (1 KB/wave-instr); c0 decorrelates which channel-plane each block
// reads at any instant (49 coprime 64 -> c0 uniform over residues), spreading
// instantaneous DRAM demand across the full 411 MB instead of a few planes.
__global__ __launch_bounds__(256) void k_mean(const float* __restrict__ x,
                                              float* __restrict__ a) {
    int b = blockIdx.x / 49;                      // 49 blocks per image
    int i = (blockIdx.x % 49) * 256 + threadIdx.x;
    const f4v* x4 = reinterpret_cast<const f4v*>(x) + (size_t)b * C_ * HW4_ + i;
    f4v s = {0.f, 0.f, 0.f, 0.f};
    int c0 = blockIdx.x & 63;
    #pragma unroll 8
    for (int c = c0; c < C_; ++c) {
        s += x4[(size_t)c * HW4_];
    }
    #pragma unroll 8
    for (int c = 0; c < c0; ++c) {
        s += x4[(size_t)c * HW4_];
    }
    s *= (1.0f / 64.0f);
    reinterpret_cast<f4v*>(a)[(size_t)b * HW4_ + i] = s;
}

// X-macro over the 36 channel pairs (g, ch0, ch1) — all compile-time literals.
#define PAIR_LIST(OP) \
  OP(0,0,1) OP(1,0,2) OP(2,0,3) OP(3,0,4) OP(4,0,5) OP(5,0,6) OP(6,0,7) OP(7,0,8) \
  OP(8,1,2) OP(9,1,3) OP(10,1,4) OP(11,1,5) OP(12,1,6) OP(13,1,7) OP(14,1,8) \
  OP(15,2,3) OP(16,2,4) OP(17,2,5) OP(18,2,6) OP(19,2,7) OP(20,2,8) \
  OP(21,3,4) OP(22,3,5) OP(23,3,6) OP(24,3,7) OP(25,3,8) \
  OP(26,4,5) OP(27,4,6) OP(28,4,7) OP(29,4,8) \
  OP(30,5,6) OP(31,5,7) OP(32,5,8) \
  OP(33,6,7) OP(34,6,8) OP(35,7,8)

// Stage 10 clamped rows of a[b] (band r0-1 .. r0+8) into LDS buffer `bufp`.
#define STAGE_BAND(bufp) do { \
    const f4v* ab4 = reinterpret_cast<const f4v*>(a + (size_t)b * HW_); \
    _Pragma("unroll") \
    for (int k = 0; k < 3; ++k) { \
        int q = k * 256 + t; \
        if (q < 10 * (W_/4)) { \
            int row = q / (W_/4); \
            int c4  = q - row * (W_/4); \
            int gr = r0 - 1 + row; \
            gr = gr < 0 ? 0 : (gr > H_-1 ? H_-1 : gr); \
            *reinterpret_cast<f4v*>(&(bufp)[row * W_ + c4 * 4]) = ab4[gr * (W_/4) + c4]; \
        } \
    } } while (0)

// Per-pixel GLCM channel aliases (sliding window):
// n0=(r,c)  n1=(r,c+1)  n2=(r+1,c)  n3=(r+1,c+1)  n4=(r,c-1)
// n5=(r-1,c)  n6=n3  n7=(r-1,c+1)  n8=(r-1,c-1).  (r+1,c-1) never used.

// ---------------- kernel 2: per-(b,chunk) partial sums ----------------
__global__ __launch_bounds__(256) void k_sums(const float* __restrict__ a,
                                              const float* __restrict__ gw,
                                              const float* __restrict__ bng_g, const float* __restrict__ bng_b,
                                              const float* __restrict__ bng_m, const float* __restrict__ bng_v,
                                              float* __restrict__ partial) {
    int b = blockIdx.x / CHUNKS_;
    int chunk = blockIdx.x % CHUNKS_;
    int t = threadIdx.x;
    __shared__ float sA0[G_], sA1[G_], sB[G_];
    // unioned: phase A = 10-row stage band (2240 floats); phase B = acc transpose (256*37)
    __shared__ float buf[256 * 37];   // 37.0 KB
    __shared__ float red2[4 * G_];
    if (t < G_) {
        float sg = bng_g[t] / sqrtf(bng_v[t] + 1e-5f);
        sA0[t] = gw[2*t+0] * sg;
        sA1[t] = gw[2*t+1] * sg;
        sB[t]  = bng_b[t] - bng_m[t] * sg;
    }
    int r0 = chunk * ROWS_;
    STAGE_BAND(buf);
    __syncthreads();

    int seg = t & 31, lr = t >> 5;
    int w0 = seg * SEGW_;
    const float* RU = &buf[lr * W_];
    const float* RC = &buf[(lr+1) * W_];
    const float* RD = &buf[(lr+2) * W_];

    #define LOADC(g,i0,i1) float A0##g = sA0[g], A1##g = sA1[g], Bc##g = sB[g];
    PAIR_LIST(LOADC)
    #undef LOADC
    #define DECLACC(g,i0,i1) float acc##g = 0.f;
    PAIR_LIST(DECLACC)
    #undef DECLACC

    int cI = w0 > 0 ? w0 - 1 : 0;
    float uL = RU[cI], cl_ = RC[cI];
    float uC = RU[w0], cc_ = RC[w0], dC = RD[w0];
    #pragma unroll
    for (int j = 0; j < SEGW_; ++j) {
        int cR = w0 + j + 1; cR = cR < W_ ? cR : W_ - 1;
        float uR = RU[cR], cr_ = RC[cR], dR = RD[cR];
        float n0 = cc_, n1 = cr_, n2 = dC, n3 = dR, n4 = cl_,
              n5 = uC, n6 = dR, n7 = uR, n8 = uL;
        #define SUM_OP(g,i0,i1) acc##g += fmaxf(fmaf(A0##g, n##i0, fmaf(A1##g, n##i1, Bc##g)), 0.f);
        PAIR_LIST(SUM_OP)
        #undef SUM_OP
        uL = uC; cl_ = cc_; uC = uR; cc_ = cr_; dC = dR;
    }

    // ---- LDS-transpose reduction ----
    __syncthreads();                      // band reads done; reuse buf
    #define WR_OP(g,i0,i1) buf[t * 37 + g] = acc##g;
    PAIR_LIST(WR_OP)
    #undef WR_OP
    __syncthreads();
    if (t < 4 * G_) {                     // 144 threads: (g, quarter)
        int g = t >> 2, q = t & 3;
        float s = 0.f;
        int base = q * 64;
        for (int i = 0; i < 64; ++i) s += buf[(base + i) * 37 + g];
        red2[g * 4 + q] = s;
    }
    __syncthreads();
    if (t < G_) {
        partial[(size_t)(b * CHUNKS_ + chunk) * G_ + t] =
            red2[4*t] + red2[4*t+1] + red2[4*t+2] + red2[4*t+3];
    }
}

// ---------------- kernel 3: final output (per-block MLP prologue + sliding window) ----------------
__global__ __launch_bounds__(256) void k_out(const float* __restrict__ a,
                                             const float* __restrict__ partial,
                                             const float* __restrict__ gw,
                                             const float* __restrict__ bng_g, const float* __restrict__ bng_b,
                                             const float* __restrict__ bng_m, const float* __restrict__ bng_v,
                                             const float* __restrict__ bn1_g, const float* __restrict__ bn1_b,
                                             const float* __restrict__ bn1_m, const float* __restrict__ bn1_v,
                                             const float* __restrict__ w1, const float* __restrict__ ca_w1,
                                             const float* __restrict__ ca_w2,
                                             float* __restrict__ out) {
    int b = blockIdx.x / CHUNKS_;
    int chunk = blockIdx.x % CHUNKS_;
    int t = threadIdx.x;
    __shared__ float sA0[G_], sA1[G_], sB[G_], sV[G_];
    __shared__ float ss1[G_], sb1[G_], meanr[G_], pooled[G_], hid[G_/2], att[G_];
    __shared__ float sm[10 * W_];
    __shared__ float sCv[1];
    if (t < G_) {
        float sg = bng_g[t] / sqrtf(bng_v[t] + 1e-5f);
        sA0[t] = gw[2*t+0] * sg;
        sA1[t] = gw[2*t+1] * sg;
        sB[t]  = bng_b[t] - bng_m[t] * sg;
        float s1 = bn1_g[t] / sqrtf(bn1_v[t] + 1e-5f);
        ss1[t] = s1;
        sb1[t] = bn1_b[t] - bn1_m[t] * s1;
        float s = 0.f;
        for (int j = 0; j < CHUNKS_; ++j) s += partial[(size_t)(b * CHUNKS_ + j) * G_ + t];
        meanr[t] = s * (1.0f / (float)HW_);
    }
    int r0 = chunk * ROWS_;
    STAGE_BAND(sm);                       // overlaps with MLP phases below
    __syncthreads();
    // ---- attention MLP for this block's image (redundant per block, L2-hot inputs) ----
    if (t < G_) {
        float s = 0.f;
        #pragma unroll
        for (int g = 0; g < G_; ++g) s += w1[t*G_ + g] * meanr[g];
        pooled[t] = fmaf(s, ss1[t], sb1[t]);
    }
    __syncthreads();
    if (t < G_/2) {
        float s = 0.f;
        #pragma unroll
        for (int o = 0; o < G_; ++o) s += pooled[o] * ca_w1[t*G_ + o];
        hid[t] = fmaxf(s, 0.f);
    }
    __syncthreads();
    if (t < G_) {
        float s = 0.f;
        #pragma unroll
        for (int k = 0; k < G_/2; ++k) s += hid[k] * ca_w2[t*(G_/2) + k];
        att[t] = 1.0f / (1.0f + expf(-s));
    }
    __syncthreads();
    if (t < G_) {
        float s = 0.f;
        #pragma unroll
        for (int o = 0; o < G_; ++o) s += att[o] * ss1[o] * w1[o*G_ + t];
        sV[t] = s;
    }
    if (t == 63) {
        float s = 0.f;
        #pragma unroll
        for (int o = 0; o < G_; ++o) s += att[o] * sb1[o];
        sCv[0] = s;
    }
    __syncthreads();

    int seg = t & 31, lr = t >> 5;
    int w0 = seg * SEGW_;
    const float* RU = &sm[lr * W_];
    const float* RC = &sm[(lr+1) * W_];
    const float* RD = &sm[(lr+2) * W_];
    float* ob = out + (size_t)b * HW_ + (r0 + lr) * W_;

    #define LOADC(g,i0,i1) float A0##g = sA0[g], A1##g = sA1[g], Bc##g = sB[g], V##g = sV[g];
    PAIR_LIST(LOADC)
    #undef LOADC
    float c0 = sCv[0];

    int cI = w0 > 0 ? w0 - 1 : 0;
    float uL = RU[cI], cl_ = RC[cI];
    float uC = RU[w0], cc_ = RC[w0], dC = RD[w0];
    #pragma unroll
    for (int j = 0; j < SEGW_; ++j) {
        int cR = w0 + j + 1; cR = cR < W_ ? cR : W_ - 1;
        float uR = RU[cR], cr_ = RC[cR], dR = RD[cR];
        float n0 = cc_, n1 = cr_, n2 = dC, n3 = dR, n4 = cl_,
              n5 = uC, n6 = dR, n7 = uR, n8 = uL;
        float s = c0;
        #define OUT_OP(g,i0,i1) s = fmaf(fmaxf(fmaf(A0##g, n##i0, fmaf(A1##g, n##i1, Bc##g)), 0.f), V##g, s);
        PAIR_LIST(OUT_OP)
        #undef OUT_OP
        ob[w0 + j] = 1.0f / (1.0f + expf(-s));
        uL = uC; cl_ = cc_; uC = uR; cc_ = cr_; dC = dR;
    }
}

extern "C" void kernel_launch(void* const* d_in, const int* in_sizes, int n_in,
                              void* d_out, int out_size, void* d_ws, size_t ws_size,
                              hipStream_t stream) {
    const float* x     = (const float*)d_in[0];
    const float* gw    = (const float*)d_in[1];
    const float* w1    = (const float*)d_in[2];
    const float* ca_w1 = (const float*)d_in[3];
    const float* ca_w2 = (const float*)d_in[4];
    const float* bng_g = (const float*)d_in[5];
    const float* bng_b = (const float*)d_in[6];
    const float* bng_m = (const float*)d_in[7];
    const float* bng_v = (const float*)d_in[8];
    const float* bn1_g = (const float*)d_in[9];
    const float* bn1_b = (const float*)d_in[10];
    const float* bn1_m = (const float*)d_in[11];
    const float* bn1_v = (const float*)d_in[12];

    float* ws      = (float*)d_ws;
    float* a       = ws;                                   // 32*50176 floats
    float* partial = a + (size_t)B_ * HW_;                 // 32*28*36

    k_mean<<<B_ * 49, 256, 0, stream>>>(x, a);
    k_sums<<<B_ * CHUNKS_, 256, 0, stream>>>(a, gw,
        bng_g, bng_b, bng_m, bng_v, partial);
    k_out<<<B_ * CHUNKS_, 256, 0, stream>>>(a, partial, gw,
        bng_g, bng_b, bng_m, bng_v, bn1_g, bn1_b, bn1_m, bn1_v,
        w1, ca_w1, ca_w2, (float*)d_out);
}

// Round 10
// 102.625 us; speedup vs baseline: 1.1463x; 1.1463x over previous
//
#include <hip/hip_runtime.h>
#include <math.h>

#define B_   32
#define C_   64
#define H_   224
#define W_   224
#define HW_  (H_*W_)          // 50176
#define HW4_ (HW_/4)          // 12544
#define G_   36
#define CHUNKS_ 28
#define ROWS_ 8               // rows per chunk; 28*8 = 224
#define SEGW_ 7               // pixels per thread segment; 32 segs * 7 = 224

typedef float f4v __attribute__((ext_vector_type(4)));

// ---------------- kernel 1: channel mean (R6 form; nt loads — single-variable test) ----------------
// x is a 411 MB read-once stream (13x aggregate L2 per iteration). Nontemporal
// loads bypass L2 read-allocate, eliminating full-cache eviction churn for
// lines that are never re-read. Store of `a` stays cached (re-read by k_sums/k_out).
__global__ __launch_bounds__(256) void k_mean(const float* __restrict__ x,
                                              float* __restrict__ a) {
    int b = blockIdx.x / 49;                      // 49 blocks per image
    int i = (blockIdx.x % 49) * 256 + threadIdx.x;
    const f4v* x4 = reinterpret_cast<const f4v*>(x) + (size_t)b * C_ * HW4_ + i;
    f4v s = {0.f, 0.f, 0.f, 0.f};
    #pragma unroll 8
    for (int c = 0; c < C_; ++c) {
        s += __builtin_nontemporal_load(x4 + (size_t)c * HW4_);
    }
    s *= (1.0f / 64.0f);
    reinterpret_cast<f4v*>(a)[(size_t)b * HW4_ + i] = s;
}

// X-macro over the 36 channel pairs (g, ch0, ch1) — all compile-time literals.
#define PAIR_LIST(OP) \
  OP(0,0,1) OP(1,0,2) OP(2,0,3) OP(3,0,4) OP(4,0,5) OP(5,0,6) OP(6,0,7) OP(7,0,8) \
  OP(8,1,2) OP(9,1,3) OP(10,1,4) OP(11,1,5) OP(12,1,6) OP(13,1,7) OP(14,1,8) \
  OP(15,2,3) OP(16,2,4) OP(17,2,5) OP(18,2,6) OP(19,2,7) OP(20,2,8) \
  OP(21,3,4) OP(22,3,5) OP(23,3,6) OP(24,3,7) OP(25,3,8) \
  OP(26,4,5) OP(27,4,6) OP(28,4,7) OP(29,4,8) \
  OP(30,5,6) OP(31,5,7) OP(32,5,8) \
  OP(33,6,7) OP(34,6,8) OP(35,7,8)

// Stage 10 clamped rows of a[b] (band r0-1 .. r0+8) into LDS buffer `bufp`.
#define STAGE_BAND(bufp) do { \
    const f4v* ab4 = reinterpret_cast<const f4v*>(a + (size_t)b * HW_); \
    _Pragma("unroll") \
    for (int k = 0; k < 3; ++k) { \
        int q = k * 256 + t; \
        if (q < 10 * (W_/4)) { \
            int row = q / (W_/4); \
            int c4  = q - row * (W_/4); \
            int gr = r0 - 1 + row; \
            gr = gr < 0 ? 0 : (gr > H_-1 ? H_-1 : gr); \
            *reinterpret_cast<f4v*>(&(bufp)[row * W_ + c4 * 4]) = ab4[gr * (W_/4) + c4]; \
        } \
    } } while (0)

// Per-pixel GLCM channel aliases (sliding window):
// n0=(r,c)  n1=(r,c+1)  n2=(r+1,c)  n3=(r+1,c+1)  n4=(r,c-1)
// n5=(r-1,c)  n6=n3  n7=(r-1,c+1)  n8=(r-1,c-1).  (r+1,c-1) never used.

// ---------------- kernel 2: per-(b,chunk) partial sums ----------------
__global__ __launch_bounds__(256) void k_sums(const float* __restrict__ a,
                                              const float* __restrict__ gw,
                                              const float* __restrict__ bng_g, const float* __restrict__ bng_b,
                                              const float* __restrict__ bng_m, const float* __restrict__ bng_v,
                                              float* __restrict__ partial) {
    int b = blockIdx.x / CHUNKS_;
    int chunk = blockIdx.x % CHUNKS_;
    int t = threadIdx.x;
    __shared__ float sA0[G_], sA1[G_], sB[G_];
    // unioned: phase A = 10-row stage band (2240 floats); phase B = acc transpose (256*37)
    __shared__ float buf[256 * 37];   // 37.0 KB
    __shared__ float red2[4 * G_];
    if (t < G_) {
        float sg = bng_g[t] / sqrtf(bng_v[t] + 1e-5f);
        sA0[t] = gw[2*t+0] * sg;
        sA1[t] = gw[2*t+1] * sg;
        sB[t]  = bng_b[t] - bng_m[t] * sg;
    }
    int r0 = chunk * ROWS_;
    STAGE_BAND(buf);
    __syncthreads();

    int seg = t & 31, lr = t >> 5;
    int w0 = seg * SEGW_;
    const float* RU = &buf[lr * W_];
    const float* RC = &buf[(lr+1) * W_];
    const float* RD = &buf[(lr+2) * W_];

    #define LOADC(g,i0,i1) float A0##g = sA0[g], A1##g = sA1[g], Bc##g = sB[g];
    PAIR_LIST(LOADC)
    #undef LOADC
    #define DECLACC(g,i0,i1) float acc##g = 0.f;
    PAIR_LIST(DECLACC)
    #undef DECLACC

    int cI = w0 > 0 ? w0 - 1 : 0;
    float uL = RU[cI], cl_ = RC[cI];
    float uC = RU[w0], cc_ = RC[w0], dC = RD[w0];
    #pragma unroll
    for (int j = 0; j < SEGW_; ++j) {
        int cR = w0 + j + 1; cR = cR < W_ ? cR : W_ - 1;
        float uR = RU[cR], cr_ = RC[cR], dR = RD[cR];
        float n0 = cc_, n1 = cr_, n2 = dC, n3 = dR, n4 = cl_,
              n5 = uC, n6 = dR, n7 = uR, n8 = uL;
        #define SUM_OP(g,i0,i1) acc##g += fmaxf(fmaf(A0##g, n##i0, fmaf(A1##g, n##i1, Bc##g)), 0.f);
        PAIR_LIST(SUM_OP)
        #undef SUM_OP
        uL = uC; cl_ = cc_; uC = uR; cc_ = cr_; dC = dR;
    }

    // ---- LDS-transpose reduction ----
    __syncthreads();                      // band reads done; reuse buf
    #define WR_OP(g,i0,i1) buf[t * 37 + g] = acc##g;
    PAIR_LIST(WR_OP)
    #undef WR_OP
    __syncthreads();
    if (t < 4 * G_) {                     // 144 threads: (g, quarter)
        int g = t >> 2, q = t & 3;
        float s = 0.f;
        int base = q * 64;
        for (int i = 0; i < 64; ++i) s += buf[(base + i) * 37 + g];
        red2[g * 4 + q] = s;
    }
    __syncthreads();
    if (t < G_) {
        partial[(size_t)(b * CHUNKS_ + chunk) * G_ + t] =
            red2[4*t] + red2[4*t+1] + red2[4*t+2] + red2[4*t+3];
    }
}

// ---------------- kernel 3: final output (per-block MLP prologue + sliding window) ----------------
__global__ __launch_bounds__(256) void k_out(const float* __restrict__ a,
                                             const float* __restrict__ partial,
                                             const float* __restrict__ gw,
                                             const float* __restrict__ bng_g, const float* __restrict__ bng_b,
                                             const float* __restrict__ bng_m, const float* __restrict__ bng_v,
                                             const float* __restrict__ bn1_g, const float* __restrict__ bn1_b,
                                             const float* __restrict__ bn1_m, const float* __restrict__ bn1_v,
                                             const float* __restrict__ w1, const float* __restrict__ ca_w1,
                                             const float* __restrict__ ca_w2,
                                             float* __restrict__ out) {
    int b = blockIdx.x / CHUNKS_;
    int chunk = blockIdx.x % CHUNKS_;
    int t = threadIdx.x;
    __shared__ float sA0[G_], sA1[G_], sB[G_], sV[G_];
    __shared__ float ss1[G_], sb1[G_], meanr[G_], pooled[G_], hid[G_/2], att[G_];
    __shared__ float sm[10 * W_];
    __shared__ float sCv[1];
    if (t < G_) {
        float sg = bng_g[t] / sqrtf(bng_v[t] + 1e-5f);
        sA0[t] = gw[2*t+0] * sg;
        sA1[t] = gw[2*t+1] * sg;
        sB[t]  = bng_b[t] - bng_m[t] * sg;
        float s1 = bn1_g[t] / sqrtf(bn1_v[t] + 1e-5f);
        ss1[t] = s1;
        sb1[t] = bn1_b[t] - bn1_m[t] * s1;
        float s = 0.f;
        for (int j = 0; j < CHUNKS_; ++j) s += partial[(size_t)(b * CHUNKS_ + j) * G_ + t];
        meanr[t] = s * (1.0f / (float)HW_);
    }
    int r0 = chunk * ROWS_;
    STAGE_BAND(sm);                       // overlaps with MLP phases below
    __syncthreads();
    // ---- attention MLP for this block's image (redundant per block, L2-hot inputs) ----
    if (t < G_) {
        float s = 0.f;
        #pragma unroll
        for (int g = 0; g < G_; ++g) s += w1[t*G_ + g] * meanr[g];
        pooled[t] = fmaf(s, ss1[t], sb1[t]);
    }
    __syncthreads();
    if (t < G_/2) {
        float s = 0.f;
        #pragma unroll
        for (int o = 0; o < G_; ++o) s += pooled[o] * ca_w1[t*G_ + o];
        hid[t] = fmaxf(s, 0.f);
    }
    __syncthreads();
    if (t < G_) {
        float s = 0.f;
        #pragma unroll
        for (int k = 0; k < G_/2; ++k) s += hid[k] * ca_w2[t*(G_/2) + k];
        att[t] = 1.0f / (1.0f + expf(-s));
    }
    __syncthreads();
    if (t < G_) {
        float s = 0.f;
        #pragma unroll
        for (int o = 0; o < G_; ++o) s += att[o] * ss1[o] * w1[o*G_ + t];
        sV[t] = s;
    }
    if (t == 63) {
        float s = 0.f;
        #pragma unroll
        for (int o = 0; o < G_; ++o) s += att[o] * sb1[o];
        sCv[0] = s;
    }
    __syncthreads();

    int seg = t & 31, lr = t >> 5;
    int w0 = seg * SEGW_;
    const float* RU = &sm[lr * W_];
    const float* RC = &sm[(lr+1) * W_];
    const float* RD = &sm[(lr+2) * W_];
    float* ob = out + (size_t)b * HW_ + (r0 + lr) * W_;

    #define LOADC(g,i0,i1) float A0##g = sA0[g], A1##g = sA1[g], Bc##g = sB[g], V##g = sV[g];
    PAIR_LIST(LOADC)
    #undef LOADC
    float c0 = sCv[0];

    int cI = w0 > 0 ? w0 - 1 : 0;
    float uL = RU[cI], cl_ = RC[cI];
    float uC = RU[w0], cc_ = RC[w0], dC = RD[w0];
    #pragma unroll
    for (int j = 0; j < SEGW_; ++j) {
        int cR = w0 + j + 1; cR = cR < W_ ? cR : W_ - 1;
        float uR = RU[cR], cr_ = RC[cR], dR = RD[cR];
        float n0 = cc_, n1 = cr_, n2 = dC, n3 = dR, n4 = cl_,
              n5 = uC, n6 = dR, n7 = uR, n8 = uL;
        float s = c0;
        #define OUT_OP(g,i0,i1) s = fmaf(fmaxf(fmaf(A0##g, n##i0, fmaf(A1##g, n##i1, Bc##g)), 0.f), V##g, s);
        PAIR_LIST(OUT_OP)
        #undef OUT_OP
        ob[w0 + j] = 1.0f / (1.0f + expf(-s));
        uL = uC; cl_ = cc_; uC = uR; cc_ = cr_; dC = dR;
    }
}

extern "C" void kernel_launch(void* const* d_in, const int* in_sizes, int n_in,
                              void* d_out, int out_size, void* d_ws, size_t ws_size,
                              hipStream_t stream) {
    const float* x     = (const float*)d_in[0];
    const float* gw    = (const float*)d_in[1];
    const float* w1    = (const float*)d_in[2];
    const float* ca_w1 = (const float*)d_in[3];
    const float* ca_w2 = (const float*)d_in[4];
    const float* bng_g = (const float*)d_in[5];
    const float* bng_b = (const float*)d_in[6];
    const float* bng_m = (const float*)d_in[7];
    const float* bng_v = (const float*)d_in[8];
    const float* bn1_g = (const float*)d_in[9];
    const float* bn1_b = (const float*)d_in[10];
    const float* bn1_m = (const float*)d_in[11];
    const float* bn1_v = (const float*)d_in[12];

    float* ws      = (float*)d_ws;
    float* a       = ws;                                   // 32*50176 floats
    float* partial = a + (size_t)B_ * HW_;                 // 32*28*36

    k_mean<<<B_ * 49, 256, 0, stream>>>(x, a);
    k_sums<<<B_ * CHUNKS_, 256, 0, stream>>>(a, gw,
        bng_g, bng_b, bng_m, bng_v, partial);
    k_out<<<B_ * CHUNKS_, 256, 0, stream>>>(a, partial, gw,
        bng_g, bng_b, bng_m, bng_v, bn1_g, bn1_b, bn1_m, bn1_v,
        w1, ca_w1, ca_w2, (float*)d_out);
}